// Round 8
// baseline (100.372 us; speedup 1.0000x reference)
//
#include <hip/hip_runtime.h>
#include <math.h>

namespace {

constexpr int BB  = 4;    // batch
constexpr int SS  = 512;  // detector bins == image size
constexpr int AA  = 180;  // angles
constexpr int PAD = 112;  // row zero-pad each side: p in [6.1, 728.9]
constexpr int RB  = SS + 2 * PAD;  // 736 entries

typedef float v2f __attribute__((ext_vector_type(2)));

// ---------------------------------------------------------------------------
// Kernel A: zero `out` + ramp filter (R4-verified math, absmax 9.77e-4).
// Grid (90, 4): block = 2 angle-columns, full K, direct stores; plus each
// block zeros a slice of out (replaces the memset node).
// ---------------------------------------------------------------------------
__global__ __launch_bounds__(256) void ramp_zero_kernel(
    const float* __restrict__ x, float* __restrict__ xf, float* __restrict__ out) {
  const int t = threadIdx.x;
  {  // zero out: 262144 float4 over 360 blocks
    const int bid = blockIdx.y * 90 + blockIdx.x;
    float4 z = make_float4(0.f, 0.f, 0.f, 0.f);
    for (int i = bid * 256 + t; i < (BB * SS * SS) / 4; i += 360 * 256)
      ((float4*)out)[i] = z;
  }

  __shared__ __align__(16) float xs[2][2][256];  // [col][m-parity][m>>1]
  __shared__ __align__(16) float G[2][528];      // per-parity scaled taps
  const int a0 = blockIdx.x * 2;
  const int b  = blockIdx.y;

  const float s  = (float)(M_PI / 360.0);
  const float cc = (float)(-2.0 / (M_PI * M_PI)) * s;
  for (int i = t; i < 528; i += 256) {
    { int kk = i;     float d = (float)(2 * kk - 511); G[0][i] = (kk < 512) ? cc / (d * d) : 0.0f; }
    { int kk = i + 1; float d = (float)(2 * kk - 511); G[1][i] = (kk < 512) ? cc / (d * d) : 0.0f; }
  }

  const float* xb = x + (size_t)b * (SS * AA) + a0;
  {
    int m = t;
    float2 v = *(const float2*)(xb + (size_t)m * AA);
    xs[0][m & 1][m >> 1] = v.x;  xs[1][m & 1][m >> 1] = v.y;
    m = t + 256;
    float2 v2 = *(const float2*)(xb + (size_t)m * AA);
    xs[0][m & 1][m >> 1] = v2.x; xs[1][m & 1][m >> 1] = v2.y;
  }
  __syncthreads();

  const int col = t >> 7;
  const int p   = (t >> 6) & 1;
  const int idx = t & 63;
  const float* Gp = G[p];
  const float* xv = xs[col][1 - p];

  float acc[4] = {0.f, 0.f, 0.f, 0.f};
  float W[8];  // W[s] = Gp[A0 + s], A0 = 4*idx + 252 - 4q; slot(r,d) = 3+r-d
  {
    const int A0 = 4 * idx + 252;
    float4 w0 = *(const float4*)(Gp + A0);
    float4 w1 = *(const float4*)(Gp + A0 + 4);
    W[0] = w0.x; W[1] = w0.y; W[2] = w0.z; W[3] = w0.w;
    W[4] = w1.x; W[5] = w1.y; W[6] = w1.z; W[7] = w1.w;
  }

#pragma unroll
  for (int q = 0; q < 64; ++q) {
    const float4 xq = *(const float4*)(xv + 4 * q);  // broadcast
    float4 nw;
    if (q != 63) nw = *(const float4*)(Gp + (4 * idx + 252 - 4 * (q + 1)));
#pragma unroll
    for (int r = 0; r < 4; ++r) {
      acc[r] = fmaf(W[3 + r], xq.x, acc[r]);
      acc[r] = fmaf(W[2 + r], xq.y, acc[r]);
      acc[r] = fmaf(W[1 + r], xq.z, acc[r]);
      acc[r] = fmaf(W[0 + r], xq.w, acc[r]);
    }
    if (q != 63) {
      W[7] = W[3]; W[6] = W[2]; W[5] = W[1]; W[4] = W[0];
      W[0] = nw.x; W[1] = nw.y; W[2] = nw.z; W[3] = nw.w;
    }
  }

  const float selfc = 0.5f * s;
  const float* xsp = xs[col][p];
  float* orow = xf + ((size_t)(b * AA + a0 + col)) * SS;
#pragma unroll
  for (int r = 0; r < 4; ++r)
    orow[p + 8 * idx + 2 * r] = fmaf(selfc, xsp[4 * idx + r], acc[r]);
}

// ---------------------------------------------------------------------------
// Kernel B: backprojection, point-reflection pairing, HIGH OCCUPANCY.
// Pair {(gx,gy),(511-gx,511-gy)}: p' = 735-p exactly; row stored interleaved
// P[j] = (row[j], row[735-j]) so one ds_read2_b64 + shared (I,w) serves both.
// R8 changes vs R7 (50us, occ 27%, DS floor 28.8us):
//  - 4 pairs/thread (was 8): grid (4,32,16) = 2048 blocks = 8/CU.
//  - SINGLE-buffer 3-row LDS (17.9KB): 8 blocks/CU co-resident = 32 waves/CU.
//  - __launch_bounds__(256,8) caps VGPR at 64 for 32 waves/CU.
//  - early-exit tiles fully outside the circle (12/128 = 9.4% of work).
// Loop: ld(g+1) [global->regs, no hazard] ; compute(g) ; barrier ; st(g+1) ;
// barrier. Global-load latency covered by compute; barrier drain hidden by
// the other 7 resident blocks.
// ---------------------------------------------------------------------------
__global__ __launch_bounds__(256, 8) void backproject_kernel(
    const float* __restrict__ xf, float* __restrict__ out) {
  __shared__ __align__(16) v2f P[3][RB];   // 17664 B
  __shared__ float2 trig[45];

  const int t     = threadIdx.x;
  const int w     = t >> 6;
  const int lane  = t & 63;
  const int tx    = blockIdx.x;     // 0..3  x-tile (64 px, left half)
  const int ty    = blockIdx.y;     // 0..31 y-tile (16 rows of pairs)
  const int b     = blockIdx.z >> 2;
  const int chunk = blockIdx.z & 3;
  const int a0    = chunk * 45;

  // early-exit tiles fully outside the circle (both mirrored px share |x|,|y|)
  {
    const float step = 2.0f / 511.0f;
    float x0 = -1.0f + (float)(tx * 64) * step, x1 = -1.0f + (float)(tx * 64 + 63) * step;
    float y0 = -1.0f + (float)(ty * 16) * step, y1 = -1.0f + (float)(ty * 16 + 15) * step;
    float mx = (x0 <= 0.f && x1 >= 0.f) ? 0.f : fminf(fabsf(x0), fabsf(x1));
    float my = (y0 <= 0.f && y1 >= 0.f) ? 0.f : fminf(fabsf(y0), fabsf(y1));
    if (mx * mx + my * my > 1.0f) return;  // out already zeroed
  }

  // zero pad entries (single buffer): 3 rows x 224 pad entries
  for (int i = t; i < 3 * 2 * PAD; i += 256) {
    int rr = i / 224;
    int o  = i - rr * 224;
    int j  = (o < PAD) ? o : (o + SS);   // [0,112) U [624,736)
    P[rr][j] = (v2f){0.f, 0.f};
  }
  if (t < 45) {
    float th = (float)(a0 + t) * (float)(M_PI / 180.0);
    float sn, cn;
    sincosf(th, &sn, &cn);
    trig[t] = make_float2(cn * 255.5f, sn * 255.5f);
  }

  const float* src = xf + ((size_t)b * AA + a0) * SS;

  // staging: thread t handles detector pair (2t, 2t+1) of each of 3 rows.
  float2 fw[3], rv[3];
  auto ld = [&](int g) {
    const float* base = src + (size_t)(g * 3) * SS;
#pragma unroll
    for (int k = 0; k < 3; ++k) {
      const float* row = base + k * SS;
      fw[k] = *(const float2*)(row + 2 * t);
      rv[k] = *(const float2*)(row + 510 - 2 * t);
    }
  };
  auto st = [&]() {
#pragma unroll
    for (int k = 0; k < 3; ++k) {
      // P[PAD+2t] = (d[2t], d[511-2t]); P[PAD+2t+1] = (d[2t+1], d[510-2t])
      float4 q = make_float4(fw[k].x, rv[k].y, fw[k].y, rv[k].x);
      *(float4*)&P[k][PAD + 2 * t] = q;  // ds_write_b128
    }
  };

  const int gx = tx * 64 + lane;    // [0,256)
  // EXACT replication of jnp.linspace(-1,1,512) + f32 mask math (no FMA!)
  const float step = 2.0f / 511.0f;
  const float xg = __fadd_rn(-1.0f, __fmul_rn((float)gx, step));
  float dy[4];  // dy = -yg (negation exact)
#pragma unroll
  for (int kk = 0; kk < 4; ++kk) {
    int gy = ty * 16 + w + 4 * kk;
    dy[kk] = -__fadd_rn(-1.0f, __fmul_rn((float)gy, step));
  }

  const float Kp = 255.5f + (float)PAD;  // 367.5
  v2f acc[4];
#pragma unroll
  for (int kk = 0; kk < 4; ++kk) acc[kk] = (v2f){0.f, 0.f};

  ld(0);
  st();
  __syncthreads();

  for (int g = 0; g < 15; ++g) {
    const bool more = (g + 1 < 15);
    if (more) ld(g + 1);  // global prefetch; latency covered by compute below
#pragma unroll
    for (int aa = 0; aa < 3; ++aa) {
      const float2 cs = trig[g * 3 + aa];
      const float base = fmaf(xg, cs.x, Kp);
      const v2f* R = P[aa];
#pragma unroll
      for (int kk = 0; kk < 4; ++kk) {
        float p = fmaf(dy[kk], cs.y, base);   // p in (6, 729)
        int   I = (int)p;                     // trunc == floor (p > 0)
#if __has_builtin(__builtin_amdgcn_fractf)
        float wq = __builtin_amdgcn_fractf(p);
#else
        float wq = p - floorf(p);
#endif
        struct { v2f a, b; } q;               // 16B @ 8B-align -> ds_read2_b64
        __builtin_memcpy(&q, R + I, 16);
        v2f d  = q.b - q.a;
        v2f wv = {wq, wq};
        acc[kk] = (acc[kk] + q.a) + wv * d;   // -> v_pk_fma/add
      }
    }
    if (more) {
      __syncthreads();   // all reads of buffer done
      st();
      __syncthreads();   // publish next group
    }
  }

  // epilogue: per-pixel masks (exact f32 replication) + predicated atomics
  const int gxm  = 511 - gx;
  const float xgm = __fadd_rn(-1.0f, __fmul_rn((float)gxm, step));
  const float xx  = __fmul_rn(xg, xg);
  const float xxm = __fmul_rn(xgm, xgm);
#pragma unroll
  for (int kk = 0; kk < 4; ++kk) {
    int gy  = ty * 16 + w + 4 * kk;
    float yg = -dy[kk];
    float s0 = __fadd_rn(xx, __fmul_rn(yg, yg));
    if (s0 <= 1.0f)
      unsafeAtomicAdd(&out[((size_t)b * SS + gy) * SS + gx], acc[kk].x);
    int gym = 511 - gy;
    float ygm = __fadd_rn(-1.0f, __fmul_rn((float)gym, step));
    float s1 = __fadd_rn(xxm, __fmul_rn(ygm, ygm));
    if (s1 <= 1.0f)
      unsafeAtomicAdd(&out[((size_t)b * SS + gym) * SS + gxm], acc[kk].y);
  }
}

}  // namespace

extern "C" void kernel_launch(void* const* d_in, const int* in_sizes, int n_in,
                              void* d_out, int out_size, void* d_ws, size_t ws_size,
                              hipStream_t stream) {
  const float* x   = (const float*)d_in[0];
  float*       out = (float*)d_out;
  float*       xf  = (float*)d_ws;  // [B][A][S] = 1.44 MB

  ramp_zero_kernel<<<dim3(AA / 2, BB), 256, 0, stream>>>(x, xf, out);
  backproject_kernel<<<dim3(4, 32, 16), 256, 0, stream>>>(xf, out);
}

// Round 10
// 97.965 us; speedup vs baseline: 1.0246x; 1.0246x over previous
//
#include <hip/hip_runtime.h>
#include <hip/hip_fp16.h>
#include <math.h>

namespace {

constexpr int BB  = 4;    // batch
constexpr int SS  = 512;  // detector bins == image size
constexpr int AA  = 180;  // angles
constexpr int PAD = 112;  // virtual pad: p in (6, 729); LDS rows are 768 entries

typedef float v2f __attribute__((ext_vector_type(2)));

// ---------------------------------------------------------------------------
// Kernel A: zero `out` + ramp filter + fp16 pair-pack.
// Conv math identical to R4-verified version (absmax 9.77e-4). After the
// register conv, y goes to LDS, then rows are packed as 512 x __half2:
//   Q[j] = (half(y[j]), half(y[511-j]))   -- (fwd, rev) in 4 B
// so kernel B's point-reflection pairing reads 8 B/sample-pair (was 16).
// ---------------------------------------------------------------------------
__global__ __launch_bounds__(256) void ramp_zero_kernel(
    const float* __restrict__ x, __half2* __restrict__ xf2, float* __restrict__ out) {
  const int t = threadIdx.x;
  {  // zero out: 262144 float4 over 360 blocks
    const int bid = blockIdx.y * 90 + blockIdx.x;
    float4 z = make_float4(0.f, 0.f, 0.f, 0.f);
    for (int i = bid * 256 + t; i < (BB * SS * SS) / 4; i += 360 * 256)
      ((float4*)out)[i] = z;
  }

  __shared__ __align__(16) float xs[2][2][256];  // [col][m-parity][m>>1]
  __shared__ __align__(16) float G[2][528];      // per-parity scaled taps
  __shared__ float yb[2][512];                   // filtered rows (both cols)
  const int a0 = blockIdx.x * 2;
  const int b  = blockIdx.y;

  const float s  = (float)(M_PI / 360.0);
  const float cc = (float)(-2.0 / (M_PI * M_PI)) * s;
  for (int i = t; i < 528; i += 256) {
    { int kk = i;     float d = (float)(2 * kk - 511); G[0][i] = (kk < 512) ? cc / (d * d) : 0.0f; }
    { int kk = i + 1; float d = (float)(2 * kk - 511); G[1][i] = (kk < 512) ? cc / (d * d) : 0.0f; }
  }

  const float* xb = x + (size_t)b * (SS * AA) + a0;
  {
    int m = t;
    float2 v = *(const float2*)(xb + (size_t)m * AA);
    xs[0][m & 1][m >> 1] = v.x;  xs[1][m & 1][m >> 1] = v.y;
    m = t + 256;
    float2 v2 = *(const float2*)(xb + (size_t)m * AA);
    xs[0][m & 1][m >> 1] = v2.x; xs[1][m & 1][m >> 1] = v2.y;
  }
  __syncthreads();

  const int col = t >> 7;
  const int p   = (t >> 6) & 1;
  const int idx = t & 63;
  const float* Gp = G[p];
  const float* xv = xs[col][1 - p];

  float acc[4] = {0.f, 0.f, 0.f, 0.f};
  float W[8];  // W[s] = Gp[A0 + s], A0 = 4*idx + 252 - 4q; slot(r,d) = 3+r-d
  {
    const int A0 = 4 * idx + 252;
    float4 w0 = *(const float4*)(Gp + A0);
    float4 w1 = *(const float4*)(Gp + A0 + 4);
    W[0] = w0.x; W[1] = w0.y; W[2] = w0.z; W[3] = w0.w;
    W[4] = w1.x; W[5] = w1.y; W[6] = w1.z; W[7] = w1.w;
  }

#pragma unroll
  for (int q = 0; q < 64; ++q) {
    const float4 xq = *(const float4*)(xv + 4 * q);  // broadcast
    float4 nw;
    if (q != 63) nw = *(const float4*)(Gp + (4 * idx + 252 - 4 * (q + 1)));
#pragma unroll
    for (int r = 0; r < 4; ++r) {
      acc[r] = fmaf(W[3 + r], xq.x, acc[r]);
      acc[r] = fmaf(W[2 + r], xq.y, acc[r]);
      acc[r] = fmaf(W[1 + r], xq.z, acc[r]);
      acc[r] = fmaf(W[0 + r], xq.w, acc[r]);
    }
    if (q != 63) {
      W[7] = W[3]; W[6] = W[2]; W[5] = W[1]; W[4] = W[0];
      W[0] = nw.x; W[1] = nw.y; W[2] = nw.z; W[3] = nw.w;
    }
  }

  // self term -> LDS row (yb is a distinct array: no barrier needed before)
  const float selfc = 0.5f * s;
  const float* xsp = xs[col][p];
#pragma unroll
  for (int r = 0; r < 4; ++r)
    yb[col][p + 8 * idx + 2 * r] = fmaf(selfc, xsp[4 * idx + r], acc[r]);
  __syncthreads();

  // pack (fwd, rev) fp16 pairs, coalesced 4B stores
  __half2* orow = xf2 + ((size_t)(b * AA + a0)) * SS;
#pragma unroll
  for (int e = 0; e < 2; ++e) {
    int j = t + e * 256;
#pragma unroll
    for (int c2 = 0; c2 < 2; ++c2)
      orow[c2 * SS + j] = __floats2half2_rn(yb[c2][j], yb[c2][511 - j]);
  }
}

// ---------------------------------------------------------------------------
// Kernel B: backprojection, point-reflection pairing, fp16 rows, DMA staging.
// Pair {(gx,gy),(511-gx,511-gy)}: entry Q[j]=(row[j],row[511-j]) makes the
// mirrored sample share (I,w):  v  = a.x + w*(b.x-a.x)
//                               v' = a.y + w*(b.y-a.y)   (same formula, packed)
// 8 B LDS read per sample-pair (R8 was 16 -> LDS-data-bound at 47.6us).
// Rows staged via global_load_lds width=16 into entries [112,624); pads
// [0,112) U [624,768) are STATIC zeros written once. Double-buffered, one
// barrier per 3-angle group; DMA latency overlapped with compute.
// Grid (4,32,16) = 2048 blocks = 8/CU; LDS 18.8KB -> 8 co-resident.
// ---------------------------------------------------------------------------
__global__ __launch_bounds__(256, 8) void backproject_kernel(
    const __half2* __restrict__ xf2, float* __restrict__ out) {
  __shared__ __align__(16) __half2 P2[2][3][768];  // 18432 B
  __shared__ float2 trig[45];

  const int t     = threadIdx.x;
  const int w     = t >> 6;
  const int lane  = t & 63;
  const int tx    = blockIdx.x;     // 0..3  x-tile (64 px, left half)
  const int ty    = blockIdx.y;     // 0..31 y-tile (16 rows of pairs)
  const int b     = blockIdx.z >> 2;
  const int chunk = blockIdx.z & 3;
  const int a0    = chunk * 45;

  // early-exit tiles fully outside the circle (mirror shares |x|,|y|)
  {
    const float step = 2.0f / 511.0f;
    float x0 = -1.0f + (float)(tx * 64) * step, x1 = -1.0f + (float)(tx * 64 + 63) * step;
    float y0 = -1.0f + (float)(ty * 16) * step, y1 = -1.0f + (float)(ty * 16 + 15) * step;
    float mx = (x0 <= 0.f && x1 >= 0.f) ? 0.f : fminf(fabsf(x0), fabsf(x1));
    float my = (y0 <= 0.f && y1 >= 0.f) ? 0.f : fminf(fabsf(y0), fabsf(y1));
    if (mx * mx + my * my > 1.0f) return;  // out already zeroed
  }

  // static zero pads: entries [0,112) U [624,768) for 2 buf x 3 rows (once)
  {
    const __half2 hz = __floats2half2_rn(0.f, 0.f);
    for (int i = t; i < 6 * 256; i += 256) {
      int slot = i >> 8;               // 0..5 = buf*3 + row
      int o    = i & 255;
      int j    = (o < PAD) ? o : (o + SS);  // [0,112) U [624,768)
      P2[slot / 3][slot % 3][j] = hz;
    }
  }
  if (t < 45) {
    float th = (float)(a0 + t) * (float)(M_PI / 180.0);
    float sn, cn;
    sincosf(th, &sn, &cn);
    trig[t] = make_float2(cn * 255.5f, sn * 255.5f);
  }

  const __half2* src = xf2 + ((size_t)b * AA + a0) * SS;

  // DMA: 3 rows x 2 segments of 1024B; wave w -> seg w, waves 0,1 -> segs 4,5.
  auto stage = [&](int g, int buf) {
    const __half2* base = src + (size_t)(g * 3) * SS;
    {
      const int sg = w;
      const __half2* gp = base + (sg >> 1) * SS + (sg & 1) * 256 + lane * 4;
      void* lp = (void*)&P2[buf][sg >> 1][PAD + (sg & 1) * 256];
      __builtin_amdgcn_global_load_lds(
          (const __attribute__((address_space(1))) void*)gp,
          (__attribute__((address_space(3))) void*)lp, 16, 0, 0);
    }
    if (w < 2) {
      const int sg = 4 + w;
      const __half2* gp = base + (sg >> 1) * SS + (sg & 1) * 256 + lane * 4;
      void* lp = (void*)&P2[buf][sg >> 1][PAD + (sg & 1) * 256];
      __builtin_amdgcn_global_load_lds(
          (const __attribute__((address_space(1))) void*)gp,
          (__attribute__((address_space(3))) void*)lp, 16, 0, 0);
    }
  };

  const int gx = tx * 64 + lane;    // [0,256)
  // EXACT f32 replication of jnp.linspace for the MASK (discontinuous);
  // p itself is continuity-safe.
  const float step = 2.0f / 511.0f;
  const float xg = __fadd_rn(-1.0f, __fmul_rn((float)gx, step));
  float dy[4];
#pragma unroll
  for (int kk = 0; kk < 4; ++kk) {
    int gy = ty * 16 + w + 4 * kk;
    dy[kk] = -__fadd_rn(-1.0f, __fmul_rn((float)gy, step));
  }

  const float Kp = 255.5f + (float)PAD;  // 367.5
  v2f acc[4];
#pragma unroll
  for (int kk = 0; kk < 4; ++kk) acc[kk] = (v2f){0.f, 0.f};

  stage(0, 0);
  __syncthreads();  // compiler drains vmcnt(0) before s_barrier -> DMA visible

  int buf = 0;
  for (int g = 0; g < 15; ++g) {
    if (g + 1 < 15) stage(g + 1, buf ^ 1);  // DMA overlaps compute below
#pragma unroll
    for (int aa = 0; aa < 3; ++aa) {
      const float2 cs = trig[g * 3 + aa];
      const float base = fmaf(xg, cs.x, Kp);
      const __half2* R = P2[buf][aa];
#pragma unroll
      for (int kk = 0; kk < 4; ++kk) {
        float p = fmaf(dy[kk], cs.y, base);   // p in (6, 729)
        int   I = (int)p;                     // trunc == floor (p > 0)
#if __has_builtin(__builtin_amdgcn_fractf)
        float wq = __builtin_amdgcn_fractf(p);
#else
        float wq = p - floorf(p);
#endif
        struct { __half2 a, b; } q;           // 8B @ 4B-align -> ds_read2_b32
        __builtin_memcpy(&q, R + I, 8);
        float2 fa = __half22float2(q.a);
        float2 fb = __half22float2(q.b);
        v2f av = {fa.x, fa.y};
        v2f dv = {fb.x - fa.x, fb.y - fa.y};
        v2f wv = {wq, wq};
        acc[kk] = (acc[kk] + av) + wv * dv;   // -> v_pk_fma/add
      }
    }
    __syncthreads();  // drains DMA (vmcnt) + publishes buf^1; reads of buf done
    buf ^= 1;
  }

  // epilogue: per-pixel masks (exact f32 replication) + predicated atomics
  const int gxm  = 511 - gx;
  const float xgm = __fadd_rn(-1.0f, __fmul_rn((float)gxm, step));
  const float xx  = __fmul_rn(xg, xg);
  const float xxm = __fmul_rn(xgm, xgm);
#pragma unroll
  for (int kk = 0; kk < 4; ++kk) {
    int gy  = ty * 16 + w + 4 * kk;
    float yg = -dy[kk];
    float s0 = __fadd_rn(xx, __fmul_rn(yg, yg));
    if (s0 <= 1.0f)
      unsafeAtomicAdd(&out[((size_t)b * SS + gy) * SS + gx], acc[kk].x);
    int gym = 511 - gy;
    float ygm = __fadd_rn(-1.0f, __fmul_rn((float)gym, step));
    float s1 = __fadd_rn(xxm, __fmul_rn(ygm, ygm));
    if (s1 <= 1.0f)
      unsafeAtomicAdd(&out[((size_t)b * SS + gym) * SS + gxm], acc[kk].y);
  }
}

}  // namespace

extern "C" void kernel_launch(void* const* d_in, const int* in_sizes, int n_in,
                              void* d_out, int out_size, void* d_ws, size_t ws_size,
                              hipStream_t stream) {
  const float* x   = (const float*)d_in[0];
  float*       out = (float*)d_out;
  __half2*     xf2 = (__half2*)d_ws;  // [B][A][512] x 4B = 1.44 MB

  ramp_zero_kernel<<<dim3(AA / 2, BB), 256, 0, stream>>>(x, xf2, out);
  backproject_kernel<<<dim3(4, 32, 16), 256, 0, stream>>>(xf2, out);
}

// Round 11
// 93.315 us; speedup vs baseline: 1.0756x; 1.0498x over previous
//
#include <hip/hip_runtime.h>
#include <hip/hip_fp16.h>
#include <math.h>

namespace {

constexpr int BB  = 4;    // batch
constexpr int SS  = 512;  // detector bins == image size
constexpr int AA  = 180;  // angles
constexpr int PAD = 112;  // virtual pad: p in (6, 729); LDS rows are 768 entries

typedef float v2f __attribute__((ext_vector_type(2)));

// ---------------------------------------------------------------------------
// Kernel A: zero `out` + ramp filter + fp16 pair-pack (R10-verified).
//   Q[j] = (half(y[j]), half(y[511-j]))  -- (fwd, rev) in 4 B
// ---------------------------------------------------------------------------
__global__ __launch_bounds__(256) void ramp_zero_kernel(
    const float* __restrict__ x, __half2* __restrict__ xf2, float* __restrict__ out) {
  const int t = threadIdx.x;
  {  // zero out: 262144 float4 over 360 blocks
    const int bid = blockIdx.y * 90 + blockIdx.x;
    float4 z = make_float4(0.f, 0.f, 0.f, 0.f);
    for (int i = bid * 256 + t; i < (BB * SS * SS) / 4; i += 360 * 256)
      ((float4*)out)[i] = z;
  }

  __shared__ __align__(16) float xs[2][2][256];  // [col][m-parity][m>>1]
  __shared__ __align__(16) float G[2][528];      // per-parity scaled taps
  __shared__ float yb[2][512];                   // filtered rows (both cols)
  const int a0 = blockIdx.x * 2;
  const int b  = blockIdx.y;

  const float s  = (float)(M_PI / 360.0);
  const float cc = (float)(-2.0 / (M_PI * M_PI)) * s;
  for (int i = t; i < 528; i += 256) {
    { int kk = i;     float d = (float)(2 * kk - 511); G[0][i] = (kk < 512) ? cc / (d * d) : 0.0f; }
    { int kk = i + 1; float d = (float)(2 * kk - 511); G[1][i] = (kk < 512) ? cc / (d * d) : 0.0f; }
  }

  const float* xb = x + (size_t)b * (SS * AA) + a0;
  {
    int m = t;
    float2 v = *(const float2*)(xb + (size_t)m * AA);
    xs[0][m & 1][m >> 1] = v.x;  xs[1][m & 1][m >> 1] = v.y;
    m = t + 256;
    float2 v2 = *(const float2*)(xb + (size_t)m * AA);
    xs[0][m & 1][m >> 1] = v2.x; xs[1][m & 1][m >> 1] = v2.y;
  }
  __syncthreads();

  const int col = t >> 7;
  const int p   = (t >> 6) & 1;
  const int idx = t & 63;
  const float* Gp = G[p];
  const float* xv = xs[col][1 - p];

  float acc[4] = {0.f, 0.f, 0.f, 0.f};
  float W[8];  // W[s] = Gp[A0 + s], A0 = 4*idx + 252 - 4q; slot(r,d) = 3+r-d
  {
    const int A0 = 4 * idx + 252;
    float4 w0 = *(const float4*)(Gp + A0);
    float4 w1 = *(const float4*)(Gp + A0 + 4);
    W[0] = w0.x; W[1] = w0.y; W[2] = w0.z; W[3] = w0.w;
    W[4] = w1.x; W[5] = w1.y; W[6] = w1.z; W[7] = w1.w;
  }

#pragma unroll
  for (int q = 0; q < 64; ++q) {
    const float4 xq = *(const float4*)(xv + 4 * q);  // broadcast
    float4 nw;
    if (q != 63) nw = *(const float4*)(Gp + (4 * idx + 252 - 4 * (q + 1)));
#pragma unroll
    for (int r = 0; r < 4; ++r) {
      acc[r] = fmaf(W[3 + r], xq.x, acc[r]);
      acc[r] = fmaf(W[2 + r], xq.y, acc[r]);
      acc[r] = fmaf(W[1 + r], xq.z, acc[r]);
      acc[r] = fmaf(W[0 + r], xq.w, acc[r]);
    }
    if (q != 63) {
      W[7] = W[3]; W[6] = W[2]; W[5] = W[1]; W[4] = W[0];
      W[0] = nw.x; W[1] = nw.y; W[2] = nw.z; W[3] = nw.w;
    }
  }

  // self term -> LDS row (yb is a distinct array: no barrier needed before)
  const float selfc = 0.5f * s;
  const float* xsp = xs[col][p];
#pragma unroll
  for (int r = 0; r < 4; ++r)
    yb[col][p + 8 * idx + 2 * r] = fmaf(selfc, xsp[4 * idx + r], acc[r]);
  __syncthreads();

  // pack (fwd, rev) fp16 pairs, coalesced 4B stores
  __half2* orow = xf2 + ((size_t)(b * AA + a0)) * SS;
#pragma unroll
  for (int e = 0; e < 2; ++e) {
    int j = t + e * 256;
#pragma unroll
    for (int c2 = 0; c2 < 2; ++c2)
      orow[c2 * SS + j] = __floats2half2_rn(yb[c2][j], yb[c2][511 - j]);
  }
}

// ---------------------------------------------------------------------------
// Kernel B: backprojection, point-reflection pairing, PACKED-fp16 lerp.
// R11 change vs R10 (42.7us, VALUBusy 62% = 26us issue, ~24 VALU/sample-pair:
// the v2f f32 lerp was scalarized): inner math in __half2 intrinsics ->
// v_pk_add_f16 / v_pk_fma_f16 (1 instr each). fp16 group accumulator
// (3 angles max, values ~0.05 -> rounding << budget) flushed to f32 per
// group. ~10 VALU + 1 ds_read2 per sample-pair.
// ---------------------------------------------------------------------------
__global__ __launch_bounds__(256, 8) void backproject_kernel(
    const __half2* __restrict__ xf2, float* __restrict__ out) {
  __shared__ __align__(16) __half2 P2[2][3][768];  // 18432 B
  __shared__ float2 trig[45];

  const int t     = threadIdx.x;
  const int w     = t >> 6;
  const int lane  = t & 63;
  const int tx    = blockIdx.x;     // 0..3  x-tile (64 px, left half)
  const int ty    = blockIdx.y;     // 0..31 y-tile (16 rows of pairs)
  const int b     = blockIdx.z >> 2;
  const int chunk = blockIdx.z & 3;
  const int a0    = chunk * 45;

  // early-exit tiles fully outside the circle (mirror shares |x|,|y|)
  {
    const float step = 2.0f / 511.0f;
    float x0 = -1.0f + (float)(tx * 64) * step, x1 = -1.0f + (float)(tx * 64 + 63) * step;
    float y0 = -1.0f + (float)(ty * 16) * step, y1 = -1.0f + (float)(ty * 16 + 15) * step;
    float mx = (x0 <= 0.f && x1 >= 0.f) ? 0.f : fminf(fabsf(x0), fabsf(x1));
    float my = (y0 <= 0.f && y1 >= 0.f) ? 0.f : fminf(fabsf(y0), fabsf(y1));
    if (mx * mx + my * my > 1.0f) return;  // out already zeroed
  }

  // static zero pads: entries [0,112) U [624,768) for 2 buf x 3 rows (once)
  {
    const __half2 hz = __floats2half2_rn(0.f, 0.f);
    for (int i = t; i < 6 * 256; i += 256) {
      int slot = i >> 8;               // 0..5 = buf*3 + row
      int o    = i & 255;
      int j    = (o < PAD) ? o : (o + SS);  // [0,112) U [624,768)
      P2[slot / 3][slot % 3][j] = hz;
    }
  }
  if (t < 45) {
    float th = (float)(a0 + t) * (float)(M_PI / 180.0);
    float sn, cn;
    sincosf(th, &sn, &cn);
    trig[t] = make_float2(cn * 255.5f, sn * 255.5f);
  }

  const __half2* src = xf2 + ((size_t)b * AA + a0) * SS;

  // DMA: 3 rows x 2 segments of 1024B; wave w -> seg w, waves 0,1 -> segs 4,5.
  auto stage = [&](int g, int buf) {
    const __half2* base = src + (size_t)(g * 3) * SS;
    {
      const int sg = w;
      const __half2* gp = base + (sg >> 1) * SS + (sg & 1) * 256 + lane * 4;
      void* lp = (void*)&P2[buf][sg >> 1][PAD + (sg & 1) * 256];
      __builtin_amdgcn_global_load_lds(
          (const __attribute__((address_space(1))) void*)gp,
          (__attribute__((address_space(3))) void*)lp, 16, 0, 0);
    }
    if (w < 2) {
      const int sg = 4 + w;
      const __half2* gp = base + (sg >> 1) * SS + (sg & 1) * 256 + lane * 4;
      void* lp = (void*)&P2[buf][sg >> 1][PAD + (sg & 1) * 256];
      __builtin_amdgcn_global_load_lds(
          (const __attribute__((address_space(1))) void*)gp,
          (__attribute__((address_space(3))) void*)lp, 16, 0, 0);
    }
  };

  const int gx = tx * 64 + lane;    // [0,256)
  // EXACT f32 replication of jnp.linspace for the MASK (discontinuous);
  // p itself is continuity-safe.
  const float step = 2.0f / 511.0f;
  const float xg = __fadd_rn(-1.0f, __fmul_rn((float)gx, step));
  float dy[4];
#pragma unroll
  for (int kk = 0; kk < 4; ++kk) {
    int gy = ty * 16 + w + 4 * kk;
    dy[kk] = -__fadd_rn(-1.0f, __fmul_rn((float)gy, step));
  }

  const float Kp = 255.5f + (float)PAD;  // 367.5
  v2f acc[4];
#pragma unroll
  for (int kk = 0; kk < 4; ++kk) acc[kk] = (v2f){0.f, 0.f};

  stage(0, 0);
  __syncthreads();  // compiler drains vmcnt(0) before s_barrier -> DMA visible

  const __half2 hz2 = __floats2half2_rn(0.f, 0.f);
  int buf = 0;
  for (int g = 0; g < 15; ++g) {
    if (g + 1 < 15) stage(g + 1, buf ^ 1);  // DMA overlaps compute below
    __half2 gacc[4] = {hz2, hz2, hz2, hz2};  // fp16 group accumulator
#pragma unroll
    for (int aa = 0; aa < 3; ++aa) {
      const float2 cs = trig[g * 3 + aa];
      const float base = fmaf(xg, cs.x, Kp);
      const __half2* R = P2[buf][aa];
#pragma unroll
      for (int kk = 0; kk < 4; ++kk) {
        float p = fmaf(dy[kk], cs.y, base);   // p in (6, 729)
        int   I = (int)p;                     // trunc == floor (p > 0)
#if __has_builtin(__builtin_amdgcn_fractf)
        float wq = __builtin_amdgcn_fractf(p);
#else
        float wq = p - floorf(p);
#endif
        struct { __half2 a, b; } q;           // 8B @ 4B-align -> ds_read2_b32
        __builtin_memcpy(&q, R + I, 8);
        __half2 dv  = __hsub2(q.b, q.a);      // v_pk_add_f16 (neg)
        __half2 wh2 = __floats2half2_rn(wq, wq);
        gacc[kk] = __hadd2(gacc[kk], __hfma2(wh2, dv, q.a));  // 2x v_pk
      }
    }
    // flush fp16 group accumulator to f32 (3 samples max: values ~0.05)
#pragma unroll
    for (int kk = 0; kk < 4; ++kk) {
      float2 f = __half22float2(gacc[kk]);
      acc[kk].x += f.x;
      acc[kk].y += f.y;
    }
    __syncthreads();  // drains DMA (vmcnt) + publishes buf^1; reads of buf done
    buf ^= 1;
  }

  // epilogue: per-pixel masks (exact f32 replication) + predicated atomics
  const int gxm  = 511 - gx;
  const float xgm = __fadd_rn(-1.0f, __fmul_rn((float)gxm, step));
  const float xx  = __fmul_rn(xg, xg);
  const float xxm = __fmul_rn(xgm, xgm);
#pragma unroll
  for (int kk = 0; kk < 4; ++kk) {
    int gy  = ty * 16 + w + 4 * kk;
    float yg = -dy[kk];
    float s0 = __fadd_rn(xx, __fmul_rn(yg, yg));
    if (s0 <= 1.0f)
      unsafeAtomicAdd(&out[((size_t)b * SS + gy) * SS + gx], acc[kk].x);
    int gym = 511 - gy;
    float ygm = __fadd_rn(-1.0f, __fmul_rn((float)gym, step));
    float s1 = __fadd_rn(xxm, __fmul_rn(ygm, ygm));
    if (s1 <= 1.0f)
      unsafeAtomicAdd(&out[((size_t)b * SS + gym) * SS + gxm], acc[kk].y);
  }
}

}  // namespace

extern "C" void kernel_launch(void* const* d_in, const int* in_sizes, int n_in,
                              void* d_out, int out_size, void* d_ws, size_t ws_size,
                              hipStream_t stream) {
  const float* x   = (const float*)d_in[0];
  float*       out = (float*)d_out;
  __half2*     xf2 = (__half2*)d_ws;  // [B][A][512] x 4B = 1.44 MB

  ramp_zero_kernel<<<dim3(AA / 2, BB), 256, 0, stream>>>(x, xf2, out);
  backproject_kernel<<<dim3(4, 32, 16), 256, 0, stream>>>(xf2, out);
}